// Round 9
// baseline (136.132 us; speedup 1.0000x reference)
//
#include <hip/hip_runtime.h>
#include <hip/hip_bf16.h>
#include <cmath>

#define N_NODES 2000
#define BS 8

typedef __attribute__((ext_vector_type(8))) short short8v;
typedef __attribute__((ext_vector_type(4))) float float4v;

__device__ __forceinline__ float elu_f(float v) { return v > 0.f ? v : expm1f(v); }

__device__ __forceinline__ unsigned short f32_bf16u(float f) {
    __hip_bfloat16 h = __float2bfloat16(f);
    unsigned short u;
    __builtin_memcpy(&u, &h, 2);
    return u;
}
__device__ __forceinline__ short f32_bf16(float f) { return (short)f32_bf16u(f); }

// w = mask_bit(lane) ? w : 0 — wave-uniform 64-bit mask as lane predicate (proven)
__device__ __forceinline__ float sel_mask(float w, unsigned long long m) {
    float r;
    asm("v_cndmask_b32 %0, 0, %1, %2" : "=v"(r) : "v"(w), "s"(m));
    return r;
}

// ---------------- pack: adj bitmasks (u64 + u32, transposed) + hT pad zero ----------
__global__ __launch_bounds__(256) void pack_kernel(
    const float* __restrict__ adj,
    unsigned long long* __restrict__ maskT, unsigned* __restrict__ maskT32,
    short* __restrict__ hT) {
    int bx = blockIdx.x;
    int tid = threadIdx.x;
    if (bx < N_NODES) {
        int row = bx;
        int lane = tid & 63, wv = tid >> 6;
        for (int wq = wv; wq < 32; wq += 4) {
            int j = wq * 64 + lane;
            bool on = (j < N_NODES) && (adj[(size_t)row * N_NODES + j] > 0.f);
            unsigned long long bal = __ballot(on);
            if (lane == 0) {
                maskT[(size_t)wq * 2048 + row] = bal;
                maskT32[(size_t)(2 * wq) * 2048 + row] = (unsigned)bal;
                maskT32[(size_t)(2 * wq + 1) * 2048 + row] = (unsigned)(bal >> 32);
            }
        }
        return;
    }
    // zero hT padding columns [2000,2048) for all 24 bh x 16 f
    for (int i = tid; i < 24 * 16 * 48; i += 256) {
        int bh = i / 768, rem = i % 768, f = rem / 48, n = N_NODES + rem % 48;
        hT[((size_t)bh * 16 + f) * 2048 + n] = 0;
    }
}

// ---------------- att1 v2: 2 heads/block, LDS x + bf16-packed PQ, analytic md -------
__global__ __launch_bounds__(256) void att1_kernel(
    const unsigned long long* __restrict__ maskT,
    const float* __restrict__ x,
    const float* __restrict__ W1, const float* __restrict__ a1,
    float* __restrict__ o1) {
    __shared__ unsigned sPQ[2][2048];
    __shared__ float sX[2048];
    __shared__ float2 redmm[256];
    int tid = threadIdx.x;
    int by = blockIdx.y, b = blockIdx.z;

    // stage x + min/max
    float mn = 1e30f, mx = -1e30f;
    for (int n = tid; n < 2048; n += 256) {
        float xv = (n < N_NODES) ? x[(size_t)b * N_NODES + n] : 0.f;
        sX[n] = xv;
        if (n < N_NODES) { mn = fminf(mn, xv); mx = fmaxf(mx, xv); }
    }
    redmm[tid] = make_float2(mn, mx);
    __syncthreads();
    for (int s = 128; s > 0; s >>= 1) {
        if (tid < s) {
            redmm[tid].x = fminf(redmm[tid].x, redmm[tid + s].x);
            redmm[tid].y = fmaxf(redmm[tid].y, redmm[tid + s].y);
        }
        __syncthreads();
    }
    float xmin = redmm[0].x, xmax = redmm[0].y;

    // per-head ws/wd/md (analytic colmax: d = wd*x)
    float wsv[2], wdv[2], md[2];
    #pragma unroll
    for (int hh = 0; hh < 2; ++hh) {
        int head = by * 2 + hh;
        float ws = 0.f, wd = 0.f;
        #pragma unroll
        for (int f = 0; f < 8; ++f) {
            float wv = W1[head * 8 + f];
            ws = fmaf(wv, a1[head * 16 + f], ws);
            wd = fmaf(wv, a1[head * 16 + 8 + f], wd);
        }
        wsv[hh] = ws; wdv[hh] = wd;
        md[hh] = wd >= 0.f ? wd * xmax : wd * xmin;
    }

    // fill packed P/Q (bf16 pair: P in high 16, Q in low 16)
    for (int n = tid; n < 2048; n += 256) {
        float xv = sX[n];
        #pragma unroll
        for (int hh = 0; hh < 2; ++hh) {
            unsigned v = 0;
            if (n < N_NODES) {
                float d = wdv[hh] * xv - md[hh];
                unsigned Pb = f32_bf16u(__expf(d));
                unsigned Qb = f32_bf16u(__expf(0.2f * d));
                v = (Pb << 16) | Qb;
            }
            sPQ[hh][n] = v;
        }
    }
    __syncthreads();

    int lane = tid & 63;
    int wave = __builtin_amdgcn_readfirstlane(tid >> 6);
    int t = blockIdx.x * 4 + wave;
    if (t >= 250) return;
    int row0 = t * 8;

    float A_[2][8], B_[2][8], num[2][8], den[2][8];
    #pragma unroll
    for (int hh = 0; hh < 2; ++hh) {
        #pragma unroll
        for (int r = 0; r < 8; ++r) {
            float sv = wsv[hh] * sX[row0 + r];
            float u = sv + md[hh], ub = fmaxf(u, 0.2f * u);
            A_[hh][r] = __expf(u - ub);
            B_[hh][r] = __expf(0.2f * u - ub);
            num[hh][r] = 0.f; den[hh][r] = 0.f;
        }
    }

    for (int j0 = 0; j0 < 2048; j0 += 64) {
        int j = j0 + lane;
        unsigned pq0 = sPQ[0][j];
        unsigned pq1 = sPQ[1][j];
        float xv = sX[j];
        float P0 = __uint_as_float(pq0 & 0xFFFF0000u);
        float Q0 = __uint_as_float(pq0 << 16);
        float P1 = __uint_as_float(pq1 & 0xFFFF0000u);
        float Q1 = __uint_as_float(pq1 << 16);
        const unsigned long long* mrow = maskT + ((size_t)(j0 >> 6) << 11) + row0;
        #pragma unroll
        for (int r = 0; r < 8; ++r) {
            unsigned long long m = mrow[r];
            float w0 = fmaxf(A_[0][r] * P0, B_[0][r] * Q0);
            w0 = sel_mask(w0, m);
            num[0][r] = fmaf(w0, xv, num[0][r]);
            den[0][r] += w0;
            float w1 = fmaxf(A_[1][r] * P1, B_[1][r] * Q1);
            w1 = sel_mask(w1, m);
            num[1][r] = fmaf(w1, xv, num[1][r]);
            den[1][r] += w1;
        }
    }
    #pragma unroll
    for (int off = 32; off >= 1; off >>= 1) {
        #pragma unroll
        for (int hh = 0; hh < 2; ++hh) {
            #pragma unroll
            for (int r = 0; r < 8; ++r) {
                num[hh][r] += __shfl_xor(num[hh][r], off, 64);
                den[hh][r] += __shfl_xor(den[hh][r], off, 64);
            }
        }
    }
    if (lane < 8) {
        #pragma unroll
        for (int hh = 0; hh < 2; ++hh) {
            int head = by * 2 + hh;
            float wf = W1[head * 8 + lane];
            #pragma unroll
            for (int r = 0; r < 8; ++r) {
                float ratio = den[hh][r] > 0.f ? num[hh][r] / den[hh][r] : 0.f;
                float v = ratio * wf;
                o1[((size_t)(b * N_NODES + row0 + r)) * 32 + head * 8 + lane] =
                    v > 0.f ? v : expm1f(v);
            }
        }
    }
}

// ---------------- prep2: h2 = o1@W2 (bf16 hT [bh][f][2048]); s2/d2 ----------------
__global__ __launch_bounds__(256) void prep2_kernel(
    const float* __restrict__ o1, const float* __restrict__ W2,
    const float* __restrict__ a2,
    short* __restrict__ hT, float* __restrict__ s2, float* __restrict__ d2) {
    __shared__ float sW[1536];
    int tid = threadIdx.x;
    for (int i = tid; i < 1536; i += 256) sW[i] = W2[i];
    __syncthreads();
    int idx = blockIdx.x * 256 + tid;
    if (idx >= BS * 3 * N_NODES) return;
    int b = idx / 6000, r = idx % 6000, h = r / N_NODES, n = r % N_NODES;
    int bh = b * 3 + h;
    float in[32];
    const float4* ip = (const float4*)(o1 + ((size_t)b * N_NODES + n) * 32);
    #pragma unroll
    for (int q = 0; q < 8; ++q) {
        float4 v = ip[q];
        in[4 * q] = v.x; in[4 * q + 1] = v.y; in[4 * q + 2] = v.z; in[4 * q + 3] = v.w;
    }
    float hv[16];
    #pragma unroll
    for (int f = 0; f < 16; ++f) hv[f] = 0.f;
    #pragma unroll
    for (int k = 0; k < 32; ++k) {
        float ik = in[k];
        #pragma unroll
        for (int f = 0; f < 16; ++f) hv[f] = fmaf(ik, sW[h * 512 + k * 16 + f], hv[f]);
    }
    float sr = 0.f, ds = 0.f;
    #pragma unroll
    for (int f = 0; f < 16; ++f) {
        hT[((size_t)bh * 16 + f) * 2048 + n] = f32_bf16(hv[f]);
        sr = fmaf(hv[f], a2[h * 32 + f], sr);
        ds = fmaf(hv[f], a2[h * 32 + 16 + f], ds);
    }
    s2[(size_t)bh * N_NODES + n] = sr;
    d2[(size_t)bh * N_NODES + n] = ds;
}

// ---------------- att2: bf16 MFMA 16x16x32, in-kernel md/PQ (R8-proven) ----------------
__global__ __launch_bounds__(256) void att2_kernel(
    const unsigned* __restrict__ maskT32,
    const short* __restrict__ hT,
    const float* __restrict__ s2, const float* __restrict__ d2,
    float* __restrict__ o2) {
    __shared__ float2 sPQ[2048];
    __shared__ float red[256];
    int tid = threadIdx.x;
    int head = blockIdx.y, b = blockIdx.z, bh = b * 3 + head;
    const float* dp = d2 + (size_t)bh * N_NODES;

    float mx = -1e30f;
    for (int n = tid; n < N_NODES; n += 256) mx = fmaxf(mx, dp[n]);
    red[tid] = mx;
    __syncthreads();
    for (int s = 128; s > 0; s >>= 1) {
        if (tid < s) red[tid] = fmaxf(red[tid], red[tid + s]);
        __syncthreads();
    }
    float md = red[0];
    for (int n = tid; n < 2048; n += 256) {
        if (n < N_NODES) {
            float d = dp[n] - md;
            sPQ[n] = make_float2(__expf(d), __expf(0.2f * d));
        } else {
            sPQ[n] = make_float2(0.f, 0.f);
        }
    }
    __syncthreads();

    int lane = tid & 63;
    int wave = __builtin_amdgcn_readfirstlane(tid >> 6);
    int t = blockIdx.x * 4 + wave;
    if (t >= 125) return;
    int rs = lane & 15;      // A row in tile == C col (feature)
    int g = lane >> 4;       // k-group
    int row = t * 16 + rs;

    float sv = s2[(size_t)bh * N_NODES + row];
    float u = sv + md, ub = fmaxf(u, 0.2f * u);
    float Ar = __expf(u - ub), Br = __expf(0.2f * u - ub);
    const short* hb = hT + ((size_t)bh * 16 + rs) * 2048;

    float4v acc = {0.f, 0.f, 0.f, 0.f};
    float den = 0.f;

    for (int jc = 0; jc < 64; ++jc) {
        int jb = jc * 32 + g * 8;
        float w[8];
        #pragma unroll
        for (int e2 = 0; e2 < 4; ++e2) {
            float4 pq2 = *(const float4*)(&sPQ[jb + e2 * 2]);  // P0,Q0,P1,Q1
            w[e2 * 2 + 0] = fmaxf(Ar * pq2.x, Br * pq2.y);
            w[e2 * 2 + 1] = fmaxf(Ar * pq2.z, Br * pq2.w);
        }
        unsigned mby = maskT32[(size_t)jc * 2048 + row] >> (g * 8);
        short8v av;
        #pragma unroll
        for (int e = 0; e < 8; ++e) {
            float we = (mby & (1u << e)) ? w[e] : 0.f;
            den += we;
            av[e] = f32_bf16(we);
        }
        short8v bv = *(const short8v*)(hb + jb);
        acc = __builtin_amdgcn_mfma_f32_16x16x32_bf16(av, bv, acc, 0, 0, 0);
    }

    den += __shfl_xor(den, 16, 64);
    den += __shfl_xor(den, 32, 64);
    float inv = den > 0.f ? 1.0f / den : 0.f;   // valid for row rs

    #pragma unroll
    for (int reg = 0; reg < 4; ++reg) {
        int crow = g * 4 + reg;
        float invr = __shfl(inv, crow, 64);
        float v = acc[reg] * invr;
        v = v > 0.f ? v : expm1f(v);
        o2[((size_t)(b * N_NODES + t * 16 + crow)) * 48 + head * 16 + rs] = v;
    }
}

// ---------------- fc1 split-K with inline concat/projection staging ----------------
__global__ __launch_bounds__(256) void fc1_splitk_kernel(
    const float* __restrict__ x,
    const float* __restrict__ o1, const float* __restrict__ o2,
    const float* __restrict__ pw1, const float* __restrict__ pb1,
    const float* __restrict__ pw2, const float* __restrict__ pb2,
    const float* __restrict__ W, float* __restrict__ partial) {
    const int K = 6000, O = 600, KS = 71;
    __shared__ float sz[BS][KS];
    int tid = threadIdx.x;
    int kt = blockIdx.y;
    int k0 = kt * KS;
    int len = (k0 + KS <= K) ? KS : (K - k0);
    float pb1v = pb1[0], pb2v = pb2[0];
    for (int i = tid; i < BS * len; i += 256) {
        int bb = i / len, k = k0 + i % len;
        float v;
        if (k < 2000) {
            v = x[bb * 2000 + k];
        } else if (k < 4000) {
            const float* op = o1 + ((size_t)bb * 2000 + (k - 2000)) * 32;
            float s = pb1v;
            #pragma unroll
            for (int q = 0; q < 32; ++q) s = fmaf(op[q], pw1[q], s);
            v = s;
        } else {
            const float* op = o2 + ((size_t)bb * 2000 + (k - 4000)) * 48;
            float s = pb2v;
            #pragma unroll
            for (int q = 0; q < 48; ++q) s = fmaf(op[q], pw2[q], s);
            v = s;
        }
        sz[bb][i % len] = v;
    }
    __syncthreads();
    int o = blockIdx.x * 256 + tid;
    float acc[BS] = {0.f, 0.f, 0.f, 0.f, 0.f, 0.f, 0.f, 0.f};
    if (o < O) {
        for (int k = 0; k < len; ++k) {
            float w = W[(size_t)(k0 + k) * O + o];
            #pragma unroll
            for (int b = 0; b < BS; ++b) acc[b] = fmaf(sz[b][k], w, acc[b]);
        }
        #pragma unroll
        for (int b = 0; b < BS; ++b)
            partial[((size_t)kt * BS + b) * O + o] = acc[b];
    }
}

// ---------------- fc2 split-K with inline fc1-reduce staging — grid (1, 16) ----------
__global__ __launch_bounds__(256) void fc2_splitk_kernel(
    const float* __restrict__ p1, const float* __restrict__ b1,
    const float* __restrict__ W, float* __restrict__ partial) {
    const int K = 600, O = 256, KS = 38;
    __shared__ float sz[BS][KS];
    int tid = threadIdx.x;
    int kt = blockIdx.y;
    int k0 = kt * KS;
    int k1 = k0 + KS < K ? k0 + KS : K;
    int len = k1 - k0;
    for (int i = tid; i < BS * len; i += 256) {
        int bb = i / len, k = k0 + i % len;
        float a = b1[k];
        #pragma unroll 5
        for (int q = 0; q < 85; ++q) a += p1[((size_t)q * BS + bb) * 600 + k];
        sz[bb][i % len] = elu_f(a);
    }
    __syncthreads();
    int o = tid;
    float acc[BS] = {0.f, 0.f, 0.f, 0.f, 0.f, 0.f, 0.f, 0.f};
    for (int k = 0; k < len; ++k) {
        float w = W[(size_t)(k0 + k) * O + o];
        #pragma unroll
        for (int b = 0; b < BS; ++b) acc[b] = fmaf(sz[b][k], w, acc[b]);
    }
    #pragma unroll
    for (int b = 0; b < BS; ++b)
        partial[((size_t)kt * BS + b) * O + o] = acc[b];
}

// ---------------- fc_tail: p2-reduce + fc3 + fc4 + fc5 — grid (BS) ----------------
__global__ __launch_bounds__(256) void fc_tail_kernel(
    const float* __restrict__ p2, const float* __restrict__ b2,
    const float* __restrict__ w3, const float* __restrict__ b3,
    const float* __restrict__ w4, const float* __restrict__ b4,
    const float* __restrict__ w5, const float* __restrict__ b5,
    float* __restrict__ outp) {
    int b = blockIdx.x, tid = threadIdx.x;
    __shared__ float t2[256], red[256], z1[64], z4[32];
    {
        float a = b2[tid];
        #pragma unroll
        for (int kt = 0; kt < 16; ++kt) a += p2[((size_t)kt * BS + b) * 256 + tid];
        t2[tid] = elu_f(a);
    }
    __syncthreads();
    {
        int o = tid & 63, ks = tid >> 6;
        float a = 0.f;
        for (int k = ks; k < 256; k += 4) a = fmaf(t2[k], w3[k * 64 + o], a);
        red[tid] = a;
        __syncthreads();
        if (ks == 0) {
            float v = red[o] + red[64 + o] + red[128 + o] + red[192 + o] + b3[o];
            v = elu_f(v);
            z1[o] = v;
            outp[b * 64 + o] = v;
        }
    }
    __syncthreads();
    if (tid < 32) {
        float v = b4[tid];
        #pragma unroll
        for (int k = 0; k < 64; ++k) v = fmaf(z1[k], w4[k * 32 + tid], v);
        z4[tid] = elu_f(v);
    }
    __syncthreads();
    if (tid < 2) {
        float v = b5[tid];
        #pragma unroll
        for (int k = 0; k < 32; ++k) v = fmaf(z4[k], w5[k * 2 + tid], v);
        outp[BS * 64 + b * 2 + tid] = v;
    }
}

extern "C" void kernel_launch(void* const* d_in, const int* in_sizes, int n_in,
                              void* d_out, int out_size, void* d_ws, size_t ws_size,
                              hipStream_t stream) {
    const float* x    = (const float*)d_in[0];
    const float* adj  = (const float*)d_in[1];
    const float* W1   = (const float*)d_in[2];
    const float* a1   = (const float*)d_in[3];
    const float* W2   = (const float*)d_in[4];
    const float* a2   = (const float*)d_in[5];
    const float* pw1  = (const float*)d_in[6];
    const float* pb1  = (const float*)d_in[7];
    const float* pw2  = (const float*)d_in[8];
    const float* pb2  = (const float*)d_in[9];
    const float* fc1w = (const float*)d_in[10];
    const float* fc1b = (const float*)d_in[11];
    const float* fc2w = (const float*)d_in[12];
    const float* fc2b = (const float*)d_in[13];
    const float* fc3w = (const float*)d_in[14];
    const float* fc3b = (const float*)d_in[15];
    const float* fc4w = (const float*)d_in[16];
    const float* fc4b = (const float*)d_in[17];
    const float* fc5w = (const float*)d_in[18];
    const float* fc5b = (const float*)d_in[19];
    float* outp = (float*)d_out;

    float* ws = (float*)d_ws;
    size_t off = 0;
    auto alloc = [&](size_t n) {
        float* p = ws + off;
        off += (n + 63) & ~(size_t)63;
        return p;
    };
    float* o1 = alloc((size_t)BS * N_NODES * 32);
    float* s2 = alloc((size_t)24 * N_NODES);
    float* d2 = alloc((size_t)24 * N_NODES);
    short* hT = (short*)alloc((size_t)24 * 16 * 2048 / 2);
    float* o2 = alloc((size_t)BS * N_NODES * 48);
    const int KT1 = 85;
    float* p1 = alloc((size_t)KT1 * BS * 600);
    float* p2 = alloc((size_t)16 * BS * 256);
    unsigned long long* maskT = (unsigned long long*)alloc((size_t)32 * 2048 * 2);
    unsigned* maskT32 = (unsigned*)alloc((size_t)64 * 2048);

    pack_kernel<<<N_NODES + 1, 256, 0, stream>>>(adj, maskT, maskT32, hT);
    att1_kernel<<<dim3(63, 2, BS), 256, 0, stream>>>(maskT, x, W1, a1, o1);
    prep2_kernel<<<(BS * 3 * N_NODES + 255) / 256, 256, 0, stream>>>(o1, W2, a2, hT, s2, d2);
    att2_kernel<<<dim3(32, 3, BS), 256, 0, stream>>>(maskT32, hT, s2, d2, o2);
    fc1_splitk_kernel<<<dim3(3, KT1), 256, 0, stream>>>(
        x, o1, o2, pw1, pb1, pw2, pb2, fc1w, p1);
    fc2_splitk_kernel<<<dim3(1, 16), 256, 0, stream>>>(p1, fc1b, fc2w, p2);
    fc_tail_kernel<<<BS, 256, 0, stream>>>(
        p2, fc2b, fc3w, fc3b, fc4w, fc4b, fc5w, fc5b, outp);
}

// Round 10
// 131.215 us; speedup vs baseline: 1.0375x; 1.0375x over previous
//
#include <hip/hip_runtime.h>
#include <hip/hip_bf16.h>
#include <cmath>

#define N_NODES 2000
#define BS 8

typedef __attribute__((ext_vector_type(8))) short short8v;
typedef __attribute__((ext_vector_type(4))) float float4v;

__device__ __forceinline__ float elu_f(float v) { return v > 0.f ? v : expm1f(v); }

__device__ __forceinline__ unsigned short f32_bf16u(float f) {
    __hip_bfloat16 h = __float2bfloat16(f);
    unsigned short u;
    __builtin_memcpy(&u, &h, 2);
    return u;
}
__device__ __forceinline__ short f32_bf16(float f) { return (short)f32_bf16u(f); }

// ---------------- pack: adj bitmask (u32, transposed) + hT pad zero ----------
__global__ __launch_bounds__(256) void pack_kernel(
    const float* __restrict__ adj,
    unsigned* __restrict__ maskT32,
    short* __restrict__ hT) {
    int bx = blockIdx.x;
    int tid = threadIdx.x;
    if (bx < N_NODES) {
        int row = bx;
        int lane = tid & 63, wv = tid >> 6;
        for (int wq = wv; wq < 32; wq += 4) {
            int j = wq * 64 + lane;
            bool on = (j < N_NODES) && (adj[(size_t)row * N_NODES + j] > 0.f);
            unsigned long long bal = __ballot(on);
            if (lane == 0) {
                maskT32[(size_t)(2 * wq) * 2048 + row] = (unsigned)bal;
                maskT32[(size_t)(2 * wq + 1) * 2048 + row] = (unsigned)(bal >> 32);
            }
        }
        return;
    }
    // zero hT padding columns [2000,2048) for all 24 bh x 16 f
    for (int i = tid; i < 24 * 16 * 48; i += 256) {
        int bh = i / 768, rem = i % 768, f = rem / 48, n = N_NODES + rem % 48;
        hT[((size_t)bh * 16 + f) * 2048 + n] = 0;
    }
}

// ---------------- att1 v3: MFMA structure (mirrors proven att2), B = [x, 1, 0...] ----
// C col 0 = num, col 1 = den; out o1[b][n][32] = elu(num/den * W1[head][f])
__global__ __launch_bounds__(256) void att1_kernel(
    const unsigned* __restrict__ maskT32,
    const float* __restrict__ x,
    const float* __restrict__ W1, const float* __restrict__ a1,
    float* __restrict__ o1) {
    __shared__ float2 sPQ[2048];
    __shared__ short sXb[2048];
    __shared__ float2 redmm[256];
    int tid = threadIdx.x;
    int head = blockIdx.y, b = blockIdx.z;

    // per-head ws/wd (wave-uniform scalars)
    float ws = 0.f, wd = 0.f;
    #pragma unroll
    for (int f = 0; f < 8; ++f) {
        float wv = W1[head * 8 + f];
        ws = fmaf(wv, a1[head * 16 + f], ws);
        wd = fmaf(wv, a1[head * 16 + 8 + f], wd);
    }

    // stage bf16 x + block min/max of x
    float mn = 1e30f, mx = -1e30f;
    for (int n = tid; n < 2048; n += 256) {
        float xv = (n < N_NODES) ? x[(size_t)b * N_NODES + n] : 0.f;
        sXb[n] = f32_bf16(xv);
        if (n < N_NODES) { mn = fminf(mn, xv); mx = fmaxf(mx, xv); }
    }
    redmm[tid] = make_float2(mn, mx);
    __syncthreads();
    for (int s = 128; s > 0; s >>= 1) {
        if (tid < s) {
            redmm[tid].x = fminf(redmm[tid].x, redmm[tid + s].x);
            redmm[tid].y = fmaxf(redmm[tid].y, redmm[tid + s].y);
        }
        __syncthreads();
    }
    float md = wd >= 0.f ? wd * redmm[0].y : wd * redmm[0].x;  // max_j (wd*x_j)

    // P/Q (f32, <=1 by construction)
    for (int n = tid; n < 2048; n += 256) {
        if (n < N_NODES) {
            float d = wd * x[(size_t)b * N_NODES + n] - md;
            sPQ[n] = make_float2(__expf(d), __expf(0.2f * d));
        } else {
            sPQ[n] = make_float2(0.f, 0.f);
        }
    }
    __syncthreads();

    int lane = tid & 63;
    int wave = __builtin_amdgcn_readfirstlane(tid >> 6);
    int t = blockIdx.x * 4 + wave;
    if (t >= 125) return;
    int rs = lane & 15;      // A row in tile == C col (0=num, 1=den)
    int g = lane >> 4;       // k-group
    int row = t * 16 + rs;   // row < 2000 always (125*16 = 2000)

    float xr = x[(size_t)b * N_NODES + row];
    float u = ws * xr + md, ub = fmaxf(u, 0.2f * u);
    float Ar = __expf(u - ub), Br = __expf(0.2f * u - ub);

    // B-operand constants by lane: col rs==0 -> x (from sXb), rs==1 -> 1.0, else 0
    unsigned fill = (rs == 1) ? 0x3F803F80u : 0u;  // bf16 1.0 pair
    bool isx = (rs == 0);

    float4v acc = {0.f, 0.f, 0.f, 0.f};

    for (int jc = 0; jc < 64; ++jc) {
        int jb = jc * 32 + g * 8;
        float w[8];
        #pragma unroll
        for (int e2 = 0; e2 < 4; ++e2) {
            float4 pq2 = *(const float4*)(&sPQ[jb + e2 * 2]);  // P0,Q0,P1,Q1
            w[e2 * 2 + 0] = fmaxf(Ar * pq2.x, Br * pq2.y);
            w[e2 * 2 + 1] = fmaxf(Ar * pq2.z, Br * pq2.w);
        }
        unsigned mby = maskT32[(size_t)jc * 2048 + row] >> (g * 8);
        short8v av;
        #pragma unroll
        for (int e = 0; e < 8; ++e) {
            float we = (mby & (1u << e)) ? w[e] : 0.f;
            av[e] = f32_bf16(we);
        }
        // B fragment: bv[e] = B[k=jb+e][col=rs]
        uint4 xv4 = *(const uint4*)(sXb + jb);
        uint4 bu;
        bu.x = isx ? xv4.x : fill;
        bu.y = isx ? xv4.y : fill;
        bu.z = isx ? xv4.z : fill;
        bu.w = isx ? xv4.w : fill;
        short8v bv;
        __builtin_memcpy(&bv, &bu, 16);
        acc = __builtin_amdgcn_mfma_f32_16x16x32_bf16(av, bv, acc, 0, 0, 0);
    }

    // readout: num at lane g*16+0, den at lane g*16+1 (C: col=lane&15, row=g*4+reg)
    #pragma unroll
    for (int reg = 0; reg < 4; ++reg) {
        int crow = g * 4 + reg;
        float nm = __shfl(acc[reg], lane & 48, 64);
        float dn = __shfl(acc[reg], (lane & 48) | 1, 64);
        float ratio = dn > 0.f ? nm / dn : 0.f;
        if (rs < 8) {
            float v = ratio * W1[head * 8 + rs];
            v = v > 0.f ? v : expm1f(v);
            o1[((size_t)(b * N_NODES + t * 16 + crow)) * 32 + head * 8 + rs] = v;
        }
    }
}

// ---------------- prep2: h2 = o1@W2 (bf16 hT [bh][f][2048]); s2/d2 ----------------
__global__ __launch_bounds__(256) void prep2_kernel(
    const float* __restrict__ o1, const float* __restrict__ W2,
    const float* __restrict__ a2,
    short* __restrict__ hT, float* __restrict__ s2, float* __restrict__ d2) {
    __shared__ float sW[1536];
    int tid = threadIdx.x;
    for (int i = tid; i < 1536; i += 256) sW[i] = W2[i];
    __syncthreads();
    int idx = blockIdx.x * 256 + tid;
    if (idx >= BS * 3 * N_NODES) return;
    int b = idx / 6000, r = idx % 6000, h = r / N_NODES, n = r % N_NODES;
    int bh = b * 3 + h;
    float in[32];
    const float4* ip = (const float4*)(o1 + ((size_t)b * N_NODES + n) * 32);
    #pragma unroll
    for (int q = 0; q < 8; ++q) {
        float4 v = ip[q];
        in[4 * q] = v.x; in[4 * q + 1] = v.y; in[4 * q + 2] = v.z; in[4 * q + 3] = v.w;
    }
    float hv[16];
    #pragma unroll
    for (int f = 0; f < 16; ++f) hv[f] = 0.f;
    #pragma unroll
    for (int k = 0; k < 32; ++k) {
        float ik = in[k];
        #pragma unroll
        for (int f = 0; f < 16; ++f) hv[f] = fmaf(ik, sW[h * 512 + k * 16 + f], hv[f]);
    }
    float sr = 0.f, ds = 0.f;
    #pragma unroll
    for (int f = 0; f < 16; ++f) {
        hT[((size_t)bh * 16 + f) * 2048 + n] = f32_bf16(hv[f]);
        sr = fmaf(hv[f], a2[h * 32 + f], sr);
        ds = fmaf(hv[f], a2[h * 32 + 16 + f], ds);
    }
    s2[(size_t)bh * N_NODES + n] = sr;
    d2[(size_t)bh * N_NODES + n] = ds;
}

// ---------------- att2: bf16 MFMA 16x16x32, in-kernel md/PQ (proven) ----------------
__global__ __launch_bounds__(256) void att2_kernel(
    const unsigned* __restrict__ maskT32,
    const short* __restrict__ hT,
    const float* __restrict__ s2, const float* __restrict__ d2,
    float* __restrict__ o2) {
    __shared__ float2 sPQ[2048];
    __shared__ float red[256];
    int tid = threadIdx.x;
    int head = blockIdx.y, b = blockIdx.z, bh = b * 3 + head;
    const float* dp = d2 + (size_t)bh * N_NODES;

    float mx = -1e30f;
    for (int n = tid; n < N_NODES; n += 256) mx = fmaxf(mx, dp[n]);
    red[tid] = mx;
    __syncthreads();
    for (int s = 128; s > 0; s >>= 1) {
        if (tid < s) red[tid] = fmaxf(red[tid], red[tid + s]);
        __syncthreads();
    }
    float md = red[0];
    for (int n = tid; n < 2048; n += 256) {
        if (n < N_NODES) {
            float d = dp[n] - md;
            sPQ[n] = make_float2(__expf(d), __expf(0.2f * d));
        } else {
            sPQ[n] = make_float2(0.f, 0.f);
        }
    }
    __syncthreads();

    int lane = tid & 63;
    int wave = __builtin_amdgcn_readfirstlane(tid >> 6);
    int t = blockIdx.x * 4 + wave;
    if (t >= 125) return;
    int rs = lane & 15;      // A row in tile == C col (feature)
    int g = lane >> 4;       // k-group
    int row = t * 16 + rs;

    float sv = s2[(size_t)bh * N_NODES + row];
    float u = sv + md, ub = fmaxf(u, 0.2f * u);
    float Ar = __expf(u - ub), Br = __expf(0.2f * u - ub);
    const short* hb = hT + ((size_t)bh * 16 + rs) * 2048;

    float4v acc = {0.f, 0.f, 0.f, 0.f};
    float den = 0.f;

    for (int jc = 0; jc < 64; ++jc) {
        int jb = jc * 32 + g * 8;
        float w[8];
        #pragma unroll
        for (int e2 = 0; e2 < 4; ++e2) {
            float4 pq2 = *(const float4*)(&sPQ[jb + e2 * 2]);  // P0,Q0,P1,Q1
            w[e2 * 2 + 0] = fmaxf(Ar * pq2.x, Br * pq2.y);
            w[e2 * 2 + 1] = fmaxf(Ar * pq2.z, Br * pq2.w);
        }
        unsigned mby = maskT32[(size_t)jc * 2048 + row] >> (g * 8);
        short8v av;
        #pragma unroll
        for (int e = 0; e < 8; ++e) {
            float we = (mby & (1u << e)) ? w[e] : 0.f;
            den += we;
            av[e] = f32_bf16(we);
        }
        short8v bv = *(const short8v*)(hb + jb);
        acc = __builtin_amdgcn_mfma_f32_16x16x32_bf16(av, bv, acc, 0, 0, 0);
    }

    den += __shfl_xor(den, 16, 64);
    den += __shfl_xor(den, 32, 64);
    float inv = den > 0.f ? 1.0f / den : 0.f;   // valid for row rs

    #pragma unroll
    for (int reg = 0; reg < 4; ++reg) {
        int crow = g * 4 + reg;
        float invr = __shfl(inv, crow, 64);
        float v = acc[reg] * invr;
        v = v > 0.f ? v : expm1f(v);
        o2[((size_t)(b * N_NODES + t * 16 + crow)) * 48 + head * 16 + rs] = v;
    }
}

// ---------------- fc1 split-K with inline concat/projection staging ----------------
__global__ __launch_bounds__(256) void fc1_splitk_kernel(
    const float* __restrict__ x,
    const float* __restrict__ o1, const float* __restrict__ o2,
    const float* __restrict__ pw1, const float* __restrict__ pb1,
    const float* __restrict__ pw2, const float* __restrict__ pb2,
    const float* __restrict__ W, float* __restrict__ partial) {
    const int K = 6000, O = 600, KS = 71;
    __shared__ float sz[BS][KS];
    int tid = threadIdx.x;
    int kt = blockIdx.y;
    int k0 = kt * KS;
    int len = (k0 + KS <= K) ? KS : (K - k0);
    float pb1v = pb1[0], pb2v = pb2[0];
    for (int i = tid; i < BS * len; i += 256) {
        int bb = i / len, k = k0 + i % len;
        float v;
        if (k < 2000) {
            v = x[bb * 2000 + k];
        } else if (k < 4000) {
            const float* op = o1 + ((size_t)bb * 2000 + (k - 2000)) * 32;
            float s = pb1v;
            #pragma unroll
            for (int q = 0; q < 32; ++q) s = fmaf(op[q], pw1[q], s);
            v = s;
        } else {
            const float* op = o2 + ((size_t)bb * 2000 + (k - 4000)) * 48;
            float s = pb2v;
            #pragma unroll
            for (int q = 0; q < 48; ++q) s = fmaf(op[q], pw2[q], s);
            v = s;
        }
        sz[bb][i % len] = v;
    }
    __syncthreads();
    int o = blockIdx.x * 256 + tid;
    float acc[BS] = {0.f, 0.f, 0.f, 0.f, 0.f, 0.f, 0.f, 0.f};
    if (o < O) {
        for (int k = 0; k < len; ++k) {
            float w = W[(size_t)(k0 + k) * O + o];
            #pragma unroll
            for (int b = 0; b < BS; ++b) acc[b] = fmaf(sz[b][k], w, acc[b]);
        }
        #pragma unroll
        for (int b = 0; b < BS; ++b)
            partial[((size_t)kt * BS + b) * O + o] = acc[b];
    }
}

// ---------------- fc2 split-K with inline fc1-reduce staging — grid (1, 16) ----------
__global__ __launch_bounds__(256) void fc2_splitk_kernel(
    const float* __restrict__ p1, const float* __restrict__ b1,
    const float* __restrict__ W, float* __restrict__ partial) {
    const int K = 600, O = 256, KS = 38;
    __shared__ float sz[BS][KS];
    int tid = threadIdx.x;
    int kt = blockIdx.y;
    int k0 = kt * KS;
    int k1 = k0 + KS < K ? k0 + KS : K;
    int len = k1 - k0;
    for (int i = tid; i < BS * len; i += 256) {
        int bb = i / len, k = k0 + i % len;
        float a = b1[k];
        #pragma unroll 5
        for (int q = 0; q < 85; ++q) a += p1[((size_t)q * BS + bb) * 600 + k];
        sz[bb][i % len] = elu_f(a);
    }
    __syncthreads();
    int o = tid;
    float acc[BS] = {0.f, 0.f, 0.f, 0.f, 0.f, 0.f, 0.f, 0.f};
    for (int k = 0; k < len; ++k) {
        float w = W[(size_t)(k0 + k) * O + o];
        #pragma unroll
        for (int b = 0; b < BS; ++b) acc[b] = fmaf(sz[b][k], w, acc[b]);
    }
    #pragma unroll
    for (int b = 0; b < BS; ++b)
        partial[((size_t)kt * BS + b) * O + o] = acc[b];
}

// ---------------- fc_tail: p2-reduce + fc3 + fc4 + fc5 — grid (BS) ----------------
__global__ __launch_bounds__(256) void fc_tail_kernel(
    const float* __restrict__ p2, const float* __restrict__ b2,
    const float* __restrict__ w3, const float* __restrict__ b3,
    const float* __restrict__ w4, const float* __restrict__ b4,
    const float* __restrict__ w5, const float* __restrict__ b5,
    float* __restrict__ outp) {
    int b = blockIdx.x, tid = threadIdx.x;
    __shared__ float t2[256], red[256], z1[64], z4[32];
    {
        float a = b2[tid];
        #pragma unroll
        for (int kt = 0; kt < 16; ++kt) a += p2[((size_t)kt * BS + b) * 256 + tid];
        t2[tid] = elu_f(a);
    }
    __syncthreads();
    {
        int o = tid & 63, ks = tid >> 6;
        float a = 0.f;
        for (int k = ks; k < 256; k += 4) a = fmaf(t2[k], w3[k * 64 + o], a);
        red[tid] = a;
        __syncthreads();
        if (ks == 0) {
            float v = red[o] + red[64 + o] + red[128 + o] + red[192 + o] + b3[o];
            v = elu_f(v);
            z1[o] = v;
            outp[b * 64 + o] = v;
        }
    }
    __syncthreads();
    if (tid < 32) {
        float v = b4[tid];
        #pragma unroll
        for (int k = 0; k < 64; ++k) v = fmaf(z1[k], w4[k * 32 + tid], v);
        z4[tid] = elu_f(v);
    }
    __syncthreads();
    if (tid < 2) {
        float v = b5[tid];
        #pragma unroll
        for (int k = 0; k < 32; ++k) v = fmaf(z4[k], w5[k * 2 + tid], v);
        outp[BS * 64 + b * 2 + tid] = v;
    }
}

extern "C" void kernel_launch(void* const* d_in, const int* in_sizes, int n_in,
                              void* d_out, int out_size, void* d_ws, size_t ws_size,
                              hipStream_t stream) {
    const float* x    = (const float*)d_in[0];
    const float* adj  = (const float*)d_in[1];
    const float* W1   = (const float*)d_in[2];
    const float* a1   = (const float*)d_in[3];
    const float* W2   = (const float*)d_in[4];
    const float* a2   = (const float*)d_in[5];
    const float* pw1  = (const float*)d_in[6];
    const float* pb1  = (const float*)d_in[7];
    const float* pw2  = (const float*)d_in[8];
    const float* pb2  = (const float*)d_in[9];
    const float* fc1w = (const float*)d_in[10];
    const float* fc1b = (const float*)d_in[11];
    const float* fc2w = (const float*)d_in[12];
    const float* fc2b = (const float*)d_in[13];
    const float* fc3w = (const float*)d_in[14];
    const float* fc3b = (const float*)d_in[15];
    const float* fc4w = (const float*)d_in[16];
    const float* fc4b = (const float*)d_in[17];
    const float* fc5w = (const float*)d_in[18];
    const float* fc5b = (const float*)d_in[19];
    float* outp = (float*)d_out;

    float* ws = (float*)d_ws;
    size_t off = 0;
    auto alloc = [&](size_t n) {
        float* p = ws + off;
        off += (n + 63) & ~(size_t)63;
        return p;
    };
    float* o1 = alloc((size_t)BS * N_NODES * 32);
    float* s2 = alloc((size_t)24 * N_NODES);
    float* d2 = alloc((size_t)24 * N_NODES);
    short* hT = (short*)alloc((size_t)24 * 16 * 2048 / 2);
    float* o2 = alloc((size_t)BS * N_NODES * 48);
    const int KT1 = 85;
    float* p1 = alloc((size_t)KT1 * BS * 600);
    float* p2 = alloc((size_t)16 * BS * 256);
    unsigned* maskT32 = (unsigned*)alloc((size_t)64 * 2048);

    pack_kernel<<<N_NODES + 1, 256, 0, stream>>>(adj, maskT32, hT);
    att1_kernel<<<dim3(32, 4, BS), 256, 0, stream>>>(maskT32, x, W1, a1, o1);
    prep2_kernel<<<(BS * 3 * N_NODES + 255) / 256, 256, 0, stream>>>(o1, W2, a2, hT, s2, d2);
    att2_kernel<<<dim3(32, 3, BS), 256, 0, stream>>>(maskT32, hT, s2, d2, o2);
    fc1_splitk_kernel<<<dim3(3, KT1), 256, 0, stream>>>(
        x, o1, o2, pw1, pb1, pw2, pb2, fc1w, p1);
    fc2_splitk_kernel<<<dim3(1, 16), 256, 0, stream>>>(p1, fc1b, fc2w, p2);
    fc_tail_kernel<<<BS, 256, 0, stream>>>(
        p2, fc2b, fc3w, fc3b, fc4w, fc4b, fc5w, fc5b, outp);
}

// Round 11
// 130.328 us; speedup vs baseline: 1.0445x; 1.0068x over previous
//
#include <hip/hip_runtime.h>
#include <hip/hip_bf16.h>
#include <cmath>

#define N_NODES 2000
#define BS 8

typedef __attribute__((ext_vector_type(8))) short short8v;
typedef __attribute__((ext_vector_type(4))) float float4v;

__device__ __forceinline__ float elu_f(float v) { return v > 0.f ? v : expm1f(v); }

__device__ __forceinline__ unsigned short f32_bf16u(float f) {
    __hip_bfloat16 h = __float2bfloat16(f);
    unsigned short u;
    __builtin_memcpy(&u, &h, 2);
    return u;
}
__device__ __forceinline__ short f32_bf16(float f) { return (short)f32_bf16u(f); }

// pack two f32 -> one u32 of 2 bf16 (lo = a, hi = b)
__device__ __forceinline__ unsigned cvt_pk_bf16(float a, float b) {
    unsigned r;
    asm("v_cvt_pk_bf16_f32 %0, %1, %2" : "=v"(r) : "v"(a), "v"(b));
    return r;
}

// ---------------- pack: adj bitmask (u32, transposed) + hT pad zero ----------
__global__ __launch_bounds__(256) void pack_kernel(
    const float* __restrict__ adj,
    unsigned* __restrict__ maskT32,
    short* __restrict__ hT) {
    int bx = blockIdx.x;
    int tid = threadIdx.x;
    if (bx < N_NODES) {
        int row = bx;
        int lane = tid & 63, wv = tid >> 6;
        for (int wq = wv; wq < 32; wq += 4) {
            int j = wq * 64 + lane;
            bool on = (j < N_NODES) && (adj[(size_t)row * N_NODES + j] > 0.f);
            unsigned long long bal = __ballot(on);
            if (lane == 0) {
                maskT32[(size_t)(2 * wq) * 2048 + row] = (unsigned)bal;
                maskT32[(size_t)(2 * wq + 1) * 2048 + row] = (unsigned)(bal >> 32);
            }
        }
        return;
    }
    // zero hT padding columns [2000,2048) for all 24 bh x 16 f
    for (int i = tid; i < 24 * 16 * 48; i += 256) {
        int bh = i / 768, rem = i % 768, f = rem / 48, n = N_NODES + rem % 48;
        hT[((size_t)bh * 16 + f) * 2048 + n] = 0;
    }
}

// ---------------- att1: MFMA, B = [x, 1, 0...], w' = max(P, c*Q) (A cancels) --------
__global__ __launch_bounds__(256) void att1_kernel(
    const unsigned* __restrict__ maskT32,
    const float* __restrict__ x,
    const float* __restrict__ W1, const float* __restrict__ a1,
    float* __restrict__ o1) {
    __shared__ float2 sPQ[2048];
    __shared__ short sXb[2048];
    __shared__ float2 redmm[256];
    int tid = threadIdx.x;
    int head = blockIdx.y, b = blockIdx.z;

    // per-head ws/wd (wave-uniform scalars)
    float ws = 0.f, wd = 0.f;
    #pragma unroll
    for (int f = 0; f < 8; ++f) {
        float wv = W1[head * 8 + f];
        ws = fmaf(wv, a1[head * 16 + f], ws);
        wd = fmaf(wv, a1[head * 16 + 8 + f], wd);
    }

    // stage bf16 x + block min/max of x
    float mn = 1e30f, mx = -1e30f;
    for (int n = tid; n < 2048; n += 256) {
        float xv = (n < N_NODES) ? x[(size_t)b * N_NODES + n] : 0.f;
        sXb[n] = f32_bf16(xv);
        if (n < N_NODES) { mn = fminf(mn, xv); mx = fmaxf(mx, xv); }
    }
    redmm[tid] = make_float2(mn, mx);
    __syncthreads();
    for (int s = 128; s > 0; s >>= 1) {
        if (tid < s) {
            redmm[tid].x = fminf(redmm[tid].x, redmm[tid + s].x);
            redmm[tid].y = fmaxf(redmm[tid].y, redmm[tid + s].y);
        }
        __syncthreads();
    }
    float md = wd >= 0.f ? wd * redmm[0].y : wd * redmm[0].x;  // max_j (wd*x_j)

    // P/Q (f32, <=1 by construction)
    for (int n = tid; n < 2048; n += 256) {
        if (n < N_NODES) {
            float d = wd * x[(size_t)b * N_NODES + n] - md;
            sPQ[n] = make_float2(__expf(d), __expf(0.2f * d));
        } else {
            sPQ[n] = make_float2(0.f, 0.f);
        }
    }
    __syncthreads();

    int lane = tid & 63;
    int wave = __builtin_amdgcn_readfirstlane(tid >> 6);
    int t = blockIdx.x * 4 + wave;
    if (t >= 125) return;
    int rs = lane & 15;      // A row in tile == C col (0=num, 1=den)
    int g = lane >> 4;       // k-group
    int row = t * 16 + rs;

    float xr = x[(size_t)b * N_NODES + row];
    float u = ws * xr + md;
    float c = __expf(-0.8f * u);   // B/A; A factor cancels in num/den

    unsigned fill = (rs == 1) ? 0x3F803F80u : 0u;  // bf16 1.0 pair
    bool isx = (rs == 0);

    float4v acc = {0.f, 0.f, 0.f, 0.f};

    for (int jc = 0; jc < 64; ++jc) {
        int jb = jc * 32 + g * 8;
        float w[8];
        #pragma unroll
        for (int e2 = 0; e2 < 4; ++e2) {
            float4 pq2 = *(const float4*)(&sPQ[jb + e2 * 2]);  // P0,Q0,P1,Q1
            w[e2 * 2 + 0] = fmaxf(pq2.x, c * pq2.y);
            w[e2 * 2 + 1] = fmaxf(pq2.z, c * pq2.w);
        }
        unsigned mby = maskT32[(size_t)jc * 2048 + row] >> (g * 8);
        #pragma unroll
        for (int e = 0; e < 8; ++e)
            w[e] = (mby & (1u << e)) ? w[e] : 0.f;
        uint4 au;
        au.x = cvt_pk_bf16(w[0], w[1]);
        au.y = cvt_pk_bf16(w[2], w[3]);
        au.z = cvt_pk_bf16(w[4], w[5]);
        au.w = cvt_pk_bf16(w[6], w[7]);
        short8v av;
        __builtin_memcpy(&av, &au, 16);
        // B fragment: col rs==0 -> x, rs==1 -> 1.0, else 0
        uint4 xv4 = *(const uint4*)(sXb + jb);
        uint4 bu;
        bu.x = isx ? xv4.x : fill;
        bu.y = isx ? xv4.y : fill;
        bu.z = isx ? xv4.z : fill;
        bu.w = isx ? xv4.w : fill;
        short8v bv;
        __builtin_memcpy(&bv, &bu, 16);
        acc = __builtin_amdgcn_mfma_f32_16x16x32_bf16(av, bv, acc, 0, 0, 0);
    }

    // readout: num at lane g*16+0, den at lane g*16+1 (C: col=lane&15, row=g*4+reg)
    #pragma unroll
    for (int reg = 0; reg < 4; ++reg) {
        int crow = g * 4 + reg;
        float nm = __shfl(acc[reg], lane & 48, 64);
        float dn = __shfl(acc[reg], (lane & 48) | 1, 64);
        float ratio = dn > 0.f ? nm / dn : 0.f;
        if (rs < 8) {
            float v = ratio * W1[head * 8 + rs];
            v = v > 0.f ? v : expm1f(v);
            o1[((size_t)(b * N_NODES + t * 16 + crow)) * 32 + head * 8 + rs] = v;
        }
    }
}

// ---------------- prep2: h2 = o1@W2 (bf16 hT [bh][f][2048]); s2/d2 ----------------
__global__ __launch_bounds__(256) void prep2_kernel(
    const float* __restrict__ o1, const float* __restrict__ W2,
    const float* __restrict__ a2,
    short* __restrict__ hT, float* __restrict__ s2, float* __restrict__ d2) {
    __shared__ float sW[1536];
    int tid = threadIdx.x;
    for (int i = tid; i < 1536; i += 256) sW[i] = W2[i];
    __syncthreads();
    int idx = blockIdx.x * 256 + tid;
    if (idx >= BS * 3 * N_NODES) return;
    int b = idx / 6000, r = idx % 6000, h = r / N_NODES, n = r % N_NODES;
    int bh = b * 3 + h;
    float in[32];
    const float4* ip = (const float4*)(o1 + ((size_t)b * N_NODES + n) * 32);
    #pragma unroll
    for (int q = 0; q < 8; ++q) {
        float4 v = ip[q];
        in[4 * q] = v.x; in[4 * q + 1] = v.y; in[4 * q + 2] = v.z; in[4 * q + 3] = v.w;
    }
    float hv[16];
    #pragma unroll
    for (int f = 0; f < 16; ++f) hv[f] = 0.f;
    #pragma unroll
    for (int k = 0; k < 32; ++k) {
        float ik = in[k];
        #pragma unroll
        for (int f = 0; f < 16; ++f) hv[f] = fmaf(ik, sW[h * 512 + k * 16 + f], hv[f]);
    }
    float sr = 0.f, ds = 0.f;
    #pragma unroll
    for (int f = 0; f < 16; ++f) {
        hT[((size_t)bh * 16 + f) * 2048 + n] = f32_bf16(hv[f]);
        sr = fmaf(hv[f], a2[h * 32 + f], sr);
        ds = fmaf(hv[f], a2[h * 32 + 16 + f], ds);
    }
    s2[(size_t)bh * N_NODES + n] = sr;
    d2[(size_t)bh * N_NODES + n] = ds;
}

// ---------------- att2: bf16 MFMA, w' = max(P, c*Q), den via ones-MFMA ----------------
__global__ __launch_bounds__(256) void att2_kernel(
    const unsigned* __restrict__ maskT32,
    const short* __restrict__ hT,
    const float* __restrict__ s2, const float* __restrict__ d2,
    float* __restrict__ o2) {
    __shared__ float2 sPQ[2048];
    __shared__ float red[256];
    int tid = threadIdx.x;
    int head = blockIdx.y, b = blockIdx.z, bh = b * 3 + head;
    const float* dp = d2 + (size_t)bh * N_NODES;

    float mx = -1e30f;
    for (int n = tid; n < N_NODES; n += 256) mx = fmaxf(mx, dp[n]);
    red[tid] = mx;
    __syncthreads();
    for (int s = 128; s > 0; s >>= 1) {
        if (tid < s) red[tid] = fmaxf(red[tid], red[tid + s]);
        __syncthreads();
    }
    float md = red[0];
    for (int n = tid; n < 2048; n += 256) {
        if (n < N_NODES) {
            float d = dp[n] - md;
            sPQ[n] = make_float2(__expf(d), __expf(0.2f * d));
        } else {
            sPQ[n] = make_float2(0.f, 0.f);
        }
    }
    __syncthreads();

    int lane = tid & 63;
    int wave = __builtin_amdgcn_readfirstlane(tid >> 6);
    int t = blockIdx.x * 4 + wave;
    if (t >= 125) return;
    int rs = lane & 15;      // A row in tile == C col (feature)
    int g = lane >> 4;       // k-group
    int row = t * 16 + rs;

    float sv = s2[(size_t)bh * N_NODES + row];
    float u = sv + md;
    float c = __expf(-0.8f * u);   // A factor cancels in num/den
    const short* hb = hT + ((size_t)bh * 16 + rs) * 2048;

    const unsigned one2 = 0x3F803F80u;  // bf16 1.0 pair
    uint4 ou = make_uint4(one2, one2, one2, one2);
    short8v onesv;
    __builtin_memcpy(&onesv, &ou, 16);

    float4v acc = {0.f, 0.f, 0.f, 0.f};
    float4v accd = {0.f, 0.f, 0.f, 0.f};

    for (int jc = 0; jc < 64; ++jc) {
        int jb = jc * 32 + g * 8;
        float w[8];
        #pragma unroll
        for (int e2 = 0; e2 < 4; ++e2) {
            float4 pq2 = *(const float4*)(&sPQ[jb + e2 * 2]);  // P0,Q0,P1,Q1
            w[e2 * 2 + 0] = fmaxf(pq2.x, c * pq2.y);
            w[e2 * 2 + 1] = fmaxf(pq2.z, c * pq2.w);
        }
        unsigned mby = maskT32[(size_t)jc * 2048 + row] >> (g * 8);
        #pragma unroll
        for (int e = 0; e < 8; ++e)
            w[e] = (mby & (1u << e)) ? w[e] : 0.f;
        uint4 au;
        au.x = cvt_pk_bf16(w[0], w[1]);
        au.y = cvt_pk_bf16(w[2], w[3]);
        au.z = cvt_pk_bf16(w[4], w[5]);
        au.w = cvt_pk_bf16(w[6], w[7]);
        short8v av;
        __builtin_memcpy(&av, &au, 16);
        short8v bv = *(const short8v*)(hb + jb);
        acc = __builtin_amdgcn_mfma_f32_16x16x32_bf16(av, bv, acc, 0, 0, 0);
        accd = __builtin_amdgcn_mfma_f32_16x16x32_bf16(av, onesv, accd, 0, 0, 0);
    }

    // C layout: lane (g,rs) reg -> row g*4+reg, col rs. accd[reg] = den(row) directly.
    #pragma unroll
    for (int reg = 0; reg < 4; ++reg) {
        int crow = g * 4 + reg;
        float dn = accd[reg];
        float v = dn > 0.f ? acc[reg] / dn : 0.f;
        v = v > 0.f ? v : expm1f(v);
        o2[((size_t)(b * N_NODES + t * 16 + crow)) * 48 + head * 16 + rs] = v;
    }
}

// ---------------- fc1 split-K with inline concat/projection staging ----------------
__global__ __launch_bounds__(256) void fc1_splitk_kernel(
    const float* __restrict__ x,
    const float* __restrict__ o1, const float* __restrict__ o2,
    const float* __restrict__ pw1, const float* __restrict__ pb1,
    const float* __restrict__ pw2, const float* __restrict__ pb2,
    const float* __restrict__ W, float* __restrict__ partial) {
    const int K = 6000, O = 600, KS = 71;
    __shared__ float sz[BS][KS];
    int tid = threadIdx.x;
    int kt = blockIdx.y;
    int k0 = kt * KS;
    int len = (k0 + KS <= K) ? KS : (K - k0);
    float pb1v = pb1[0], pb2v = pb2[0];
    for (int i = tid; i < BS * len; i += 256) {
        int bb = i / len, k = k0 + i % len;
        float v;
        if (k < 2000) {
            v = x[bb * 2000 + k];
        } else if (k < 4000) {
            const float* op = o1 + ((size_t)bb * 2000 + (k - 2000)) * 32;
            float s = pb1v;
            #pragma unroll
            for (int q = 0; q < 32; ++q) s = fmaf(op[q], pw1[q], s);
            v = s;
        } else {
            const float* op = o2 + ((size_t)bb * 2000 + (k - 4000)) * 48;
            float s = pb2v;
            #pragma unroll
            for (int q = 0; q < 48; ++q) s = fmaf(op[q], pw2[q], s);
            v = s;
        }
        sz[bb][i % len] = v;
    }
    __syncthreads();
    int o = blockIdx.x * 256 + tid;
    float acc[BS] = {0.f, 0.f, 0.f, 0.f, 0.f, 0.f, 0.f, 0.f};
    if (o < O) {
        for (int k = 0; k < len; ++k) {
            float w = W[(size_t)(k0 + k) * O + o];
            #pragma unroll
            for (int b = 0; b < BS; ++b) acc[b] = fmaf(sz[b][k], w, acc[b]);
        }
        #pragma unroll
        for (int b = 0; b < BS; ++b)
            partial[((size_t)kt * BS + b) * O + o] = acc[b];
    }
}

// ---------------- fc2 split-K with inline fc1-reduce staging — grid (1, 16) ----------
__global__ __launch_bounds__(256) void fc2_splitk_kernel(
    const float* __restrict__ p1, const float* __restrict__ b1,
    const float* __restrict__ W, float* __restrict__ partial) {
    const int K = 600, O = 256, KS = 38;
    __shared__ float sz[BS][KS];
    int tid = threadIdx.x;
    int kt = blockIdx.y;
    int k0 = kt * KS;
    int k1 = k0 + KS < K ? k0 + KS : K;
    int len = k1 - k0;
    for (int i = tid; i < BS * len; i += 256) {
        int bb = i / len, k = k0 + i % len;
        float a = b1[k];
        #pragma unroll 5
        for (int q = 0; q < 85; ++q) a += p1[((size_t)q * BS + bb) * 600 + k];
        sz[bb][i % len] = elu_f(a);
    }
    __syncthreads();
    int o = tid;
    float acc[BS] = {0.f, 0.f, 0.f, 0.f, 0.f, 0.f, 0.f, 0.f};
    for (int k = 0; k < len; ++k) {
        float w = W[(size_t)(k0 + k) * O + o];
        #pragma unroll
        for (int b = 0; b < BS; ++b) acc[b] = fmaf(sz[b][k], w, acc[b]);
    }
    #pragma unroll
    for (int b = 0; b < BS; ++b)
        partial[((size_t)kt * BS + b) * O + o] = acc[b];
}

// ---------------- fc_tail: p2-reduce + fc3 + fc4 + fc5 — grid (BS) ----------------
__global__ __launch_bounds__(256) void fc_tail_kernel(
    const float* __restrict__ p2, const float* __restrict__ b2,
    const float* __restrict__ w3, const float* __restrict__ b3,
    const float* __restrict__ w4, const float* __restrict__ b4,
    const float* __restrict__ w5, const float* __restrict__ b5,
    float* __restrict__ outp) {
    int b = blockIdx.x, tid = threadIdx.x;
    __shared__ float t2[256], red[256], z1[64], z4[32];
    {
        float a = b2[tid];
        #pragma unroll
        for (int kt = 0; kt < 16; ++kt) a += p2[((size_t)kt * BS + b) * 256 + tid];
        t2[tid] = elu_f(a);
    }
    __syncthreads();
    {
        int o = tid & 63, ks = tid >> 6;
        float a = 0.f;
        for (int k = ks; k < 256; k += 4) a = fmaf(t2[k], w3[k * 64 + o], a);
        red[tid] = a;
        __syncthreads();
        if (ks == 0) {
            float v = red[o] + red[64 + o] + red[128 + o] + red[192 + o] + b3[o];
            v = elu_f(v);
            z1[o] = v;
            outp[b * 64 + o] = v;
        }
    }
    __syncthreads();
    if (tid < 32) {
        float v = b4[tid];
        #pragma unroll
        for (int k = 0; k < 64; ++k) v = fmaf(z1[k], w4[k * 32 + tid], v);
        z4[tid] = elu_f(v);
    }
    __syncthreads();
    if (tid < 2) {
        float v = b5[tid];
        #pragma unroll
        for (int k = 0; k < 32; ++k) v = fmaf(z4[k], w5[k * 2 + tid], v);
        outp[BS * 64 + b * 2 + tid] = v;
    }
}

extern "C" void kernel_launch(void* const* d_in, const int* in_sizes, int n_in,
                              void* d_out, int out_size, void* d_ws, size_t ws_size,
                              hipStream_t stream) {
    const float* x    = (const float*)d_in[0];
    const float* adj  = (const float*)d_in[1];
    const float* W1   = (const float*)d_in[2];
    const float* a1   = (const float*)d_in[3];
    const float* W2   = (const float*)d_in[4];
    const float* a2   = (const float*)d_in[5];
    const float* pw1  = (const float*)d_in[6];
    const float* pb1  = (const float*)d_in[7];
    const float* pw2  = (const float*)d_in[8];
    const float* pb2  = (const float*)d_in[9];
    const float* fc1w = (const float*)d_in[10];
    const float* fc1b = (const float*)d_in[11];
    const float* fc2w = (const float*)d_in[12];
    const float* fc2b = (const float*)d_in[13];
    const float* fc3w = (const float*)d_in[14];
    const float* fc3b = (const float*)d_in[15];
    const float* fc4w = (const float*)d_in[16];
    const float* fc4b = (const float*)d_in[17];
    const float* fc5w = (const float*)d_in[18];
    const float* fc5b = (const float*)d_in[19];
    float* outp = (float*)d_out;

    float* ws = (float*)d_ws;
    size_t off = 0;
    auto alloc = [&](size_t n) {
        float* p = ws + off;
        off += (n + 63) & ~(size_t)63;
        return p;
    };
    float* o1 = alloc((size_t)BS * N_NODES * 32);
    float* s2 = alloc((size_t)24 * N_NODES);
    float* d2 = alloc((size_t)24 * N_NODES);
    short* hT = (short*)alloc((size_t)24 * 16 * 2048 / 2);
    float* o2 = alloc((size_t)BS * N_NODES * 48);
    const int KT1 = 85;
    float* p1 = alloc((size_t)KT1 * BS * 600);
    float* p2 = alloc((size_t)16 * BS * 256);
    unsigned* maskT32 = (unsigned*)alloc((size_t)64 * 2048);

    pack_kernel<<<N_NODES + 1, 256, 0, stream>>>(adj, maskT32, hT);
    att1_kernel<<<dim3(32, 4, BS), 256, 0, stream>>>(maskT32, x, W1, a1, o1);
    prep2_kernel<<<(BS * 3 * N_NODES + 255) / 256, 256, 0, stream>>>(o1, W2, a2, hT, s2, d2);
    att2_kernel<<<dim3(32, 3, BS), 256, 0, stream>>>(maskT32, hT, s2, d2, o2);
    fc1_splitk_kernel<<<dim3(3, KT1), 256, 0, stream>>>(
        x, o1, o2, pw1, pb1, pw2, pb2, fc1w, p1);
    fc2_splitk_kernel<<<dim3(1, 16), 256, 0, stream>>>(p1, fc1b, fc2w, p2);
    fc_tail_kernel<<<BS, 256, 0, stream>>>(
        p2, fc2b, fc3w, fc3b, fc4w, fc4b, fc5w, fc5b, outp);
}